// Round 3
// baseline (9251.118 us; speedup 1.0000x reference)
//
#include <hip/hip_runtime.h>
#include <hip/hip_bf16.h>

typedef __hip_bfloat16 bf16;

// ---------- helpers ----------
__device__ __forceinline__ float LD(const float* p){ return *p; }
__device__ __forceinline__ float LD(const bf16* p){ return __bfloat162float(*p); }
__device__ __forceinline__ void ST(float* p, float v){ *p = v; }
__device__ __forceinline__ void ST(bf16* p, float v){ *p = __float2bfloat16(v); }
__device__ __forceinline__ float sigm(float v){ return 1.f/(1.f + expf(-v)); }

#define NEPS 1e-5f

// ---------- depthwise 3x3 + BN + alpha blend (one block per (b,ch) plane) ----------
__global__ __launch_bounds__(256) void dwconv_bn_blend(
        const float* __restrict__ xin, float* __restrict__ xout,
        const float* __restrict__ w, const float* __restrict__ gg, const float* __restrict__ bb,
        const float* __restrict__ mm, const float* __restrict__ vv,
        const float* __restrict__ alpha, int arow)
{
    __shared__ float tile[66*66];
    int blk = blockIdx.x;
    int ch = blk & 255;
    const float* xp = xin + (size_t)blk*4096;
    float* op = xout + (size_t)blk*4096;
    int tid = threadIdx.x;
    for (int i = tid; i < 66*66; i += 256) {
        int r = i/66, c = i%66;
        int gr = r-1, gc = c-1;
        float val = 0.f;
        if (gr >= 0 && gr < 64 && gc >= 0 && gc < 64) val = xp[gr*64+gc];
        tile[i] = val;
    }
    __syncthreads();
    float wv[9];
    #pragma unroll
    for (int k=0;k<9;k++) wv[k] = w[ch*9+k];
    float sc = gg[ch] * rsqrtf(vv[ch] + NEPS);
    float mv = mm[ch], bv = bb[ch];
    float av = sigm(alpha[arow*256+ch]);
    for (int p = tid; p < 4096; p += 256) {
        int r = p>>6, c = p&63;
        float a = 0.f;
        #pragma unroll
        for (int dr=0;dr<3;dr++)
            #pragma unroll
            for (int dc=0;dc<3;dc++)
                a += wv[dr*3+dc]*tile[(r+dr)*66 + (c+dc)];
        float bn = (a - mv)*sc + bv;
        float xv = tile[(r+1)*66 + (c+1)];
        op[p] = (1.f-av)*xv + av*bn;
    }
}

// ---------- LayerNorm stats over channel dim: mean[b,l], inv[b,l] ----------
__global__ __launch_bounds__(256) void ln_stats(const float* __restrict__ x1,
        float* __restrict__ meanp, float* __restrict__ invp)
{
    int blk = blockIdx.x;
    int b = blk >> 4;
    int l = ((blk & 15) << 8) + threadIdx.x;
    const float* xp = x1 + (size_t)b*256*4096 + l;
    float mean = 0.f, m2 = 0.f;
    for (int c=0;c<256;c++){ float v = xp[(size_t)c*4096]; mean += v; m2 += v*v; }
    mean *= (1.f/256.f); m2 *= (1.f/256.f);
    meanp[b*4096 + l] = mean;
    invp[b*4096 + l] = rsqrtf(m2 - mean*mean + NEPS);
}

// ---------- bc_dt = bcdt_w(192,256) @ LN(x1) : block = (lb, 64-px tile) ----------
template<typename TS>
__global__ __launch_bounds__(256) void bcdt_gemm(const float* __restrict__ x1,
        const float* __restrict__ meanp, const float* __restrict__ invp,
        const float* __restrict__ lnw, const float* __restrict__ lnb,
        const float* __restrict__ w, TS* __restrict__ bc, int b0)
{
    __shared__ float xt[256][64];
    int blk = blockIdx.x;
    int lb = blk >> 6;
    int b = b0 + lb;
    int l0 = (blk & 63) << 6;
    int tid = threadIdx.x;
    const float* xp = x1 + (size_t)b*256*4096 + l0;
    const float* mp = meanp + b*4096 + l0;
    const float* ip = invp + b*4096 + l0;
    for (int i=tid; i<256*64; i+=256){
        int c=i>>6, px=i&63;
        float v = xp[(size_t)c*4096+px];
        xt[c][px] = (v - mp[px])*ip[px]*lnw[c] + lnb[c];
    }
    __syncthreads();
    int lane = tid&63, g = tid>>6;
    TS* op = bc + (size_t)lb*192*4096 + l0;
    for (int i4=0; i4<12; i4++){
        int o = g*48 + i4*4;
        const float* r0 = w + (size_t)o*256;
        const float *r1 = r0+256, *r2 = r0+512, *r3 = r0+768;
        float d0=0.f,d1=0.f,d2=0.f,d3=0.f;
        #pragma unroll 8
        for (int c4=0;c4<64;c4++){
            float x0=xt[c4*4][lane], x1v=xt[c4*4+1][lane], x2v=xt[c4*4+2][lane], x3v=xt[c4*4+3][lane];
            float4 a0=((const float4*)r0)[c4], a1=((const float4*)r1)[c4];
            float4 a2=((const float4*)r2)[c4], a3=((const float4*)r3)[c4];
            d0 += a0.x*x0 + a0.y*x1v + a0.z*x2v + a0.w*x3v;
            d1 += a1.x*x0 + a1.y*x1v + a1.z*x2v + a1.w*x3v;
            d2 += a2.x*x0 + a2.y*x1v + a2.z*x2v + a2.w*x3v;
            d3 += a3.x*x0 + a3.y*x1v + a3.z*x2v + a3.w*x3v;
        }
        ST(&op[(size_t)(o+0)*4096 + lane], d0);
        ST(&op[(size_t)(o+1)*4096 + lane], d1);
        ST(&op[(size_t)(o+2)*4096 + lane], d2);
        ST(&op[(size_t)(o+3)*4096 + lane], d3);
    }
}

// ---------- plain depthwise 3x3, in-place (192 channels per batch) ----------
template<typename TS>
__global__ __launch_bounds__(256) void dwconv_plain(TS* __restrict__ data, const float* __restrict__ w)
{
    __shared__ float tile[66*66];
    int blk = blockIdx.x;
    int ch = blk % 192;
    TS* xp = data + (size_t)blk*4096;
    int tid = threadIdx.x;
    for (int i = tid; i < 66*66; i += 256) {
        int r = i/66, c = i%66;
        int gr = r-1, gc = c-1;
        float val = 0.f;
        if (gr >= 0 && gr < 64 && gc >= 0 && gc < 64) val = LD(&xp[gr*64+gc]);
        tile[i] = val;
    }
    __syncthreads();
    float wv[9];
    #pragma unroll
    for (int k=0;k<9;k++) wv[k] = w[ch*9+k];
    for (int p = tid; p < 4096; p += 256) {
        int r = p>>6, c = p&63;
        float a = 0.f;
        #pragma unroll
        for (int dr=0;dr<3;dr++)
            #pragma unroll
            for (int dc=0;dc<3;dc++)
                a += wv[dr*3+dc]*tile[(r+dr)*66 + (c+dc)];
        ST(&xp[p], a);
    }
}

// ---------- softmax over L (per (lb,s)) and AB = Am*Bm in place over Bm rows ----------
template<typename TS>
__global__ __launch_bounds__(256) void softmax_ab(TS* __restrict__ bc, const float* __restrict__ A)
{
    __shared__ float red[8];
    int blk = blockIdx.x;
    int lb = blk >> 6;
    int s = blk & 63;
    TS* dtp = bc + ((size_t)lb*192 + 128 + s)*4096;
    TS* bmp = bc + ((size_t)lb*192 + s)*4096;
    int tid = threadIdx.x;
    float Av = A[s];
    float vals[16];
    float mx = -1e30f;
    #pragma unroll
    for (int i=0;i<16;i++){ vals[i] = LD(&dtp[i*256+tid]) + Av; mx = fmaxf(mx, vals[i]); }
    #pragma unroll
    for (int o=32;o>0;o>>=1) mx = fmaxf(mx, __shfl_down(mx, o));
    int lane = tid & 63, wid = tid >> 6;
    if (lane == 0) red[wid] = mx;
    __syncthreads();
    if (tid == 0) red[4] = fmaxf(fmaxf(red[0],red[1]), fmaxf(red[2],red[3]));
    __syncthreads();
    mx = red[4];
    float sum = 0.f;
    #pragma unroll
    for (int i=0;i<16;i++){ vals[i] = expf(vals[i]-mx); sum += vals[i]; }
    #pragma unroll
    for (int o=32;o>0;o>>=1) sum += __shfl_down(sum, o);
    if (lane == 0) red[wid] = sum;
    __syncthreads();
    if (tid == 0) red[5] = red[0]+red[1]+red[2]+red[3];
    __syncthreads();
    float inv = 1.f/red[5];
    #pragma unroll
    for (int i=0;i<16;i++){
        float ab = vals[i]*inv*LD(&bmp[i*256+tid]);
        ST(&bmp[i*256+tid], ab);
    }
}

// ---------- h[lb,c,s] = sum_l LN(x1)[b,c,l]*AB[lb,s,l]  (split-L, atomic acc) ----------
template<typename TS>
__global__ __launch_bounds__(256) void h_gemm(const float* __restrict__ x1,
        const float* __restrict__ meanp, const float* __restrict__ invp,
        const float* __restrict__ lnw, const float* __restrict__ lnb,
        const TS* __restrict__ bc, float* __restrict__ h, int b0)
{
    __shared__ float xt[64][65];
    __shared__ float abt[64][64];
    int blk = blockIdx.x;
    int lb = blk >> 5;
    int b = b0 + lb;
    int ct = (blk >> 3) & 3;
    int ls = blk & 7;
    int c0 = ct*64;
    int tid = threadIdx.x;
    int lane = tid & 63, sg = tid >> 6;
    float acc[16];
    #pragma unroll
    for (int i=0;i<16;i++) acc[i]=0.f;
    for (int lc=0; lc<8; lc++){
        int lbase = ls*512 + lc*64;
        __syncthreads();
        for (int i=tid;i<4096;i+=256){
            int r=i>>6, cc=i&63;
            int l = lbase + cc;
            float v = x1[((size_t)b*256 + c0 + r)*4096 + l];
            xt[r][cc]  = (v - meanp[b*4096+l])*invp[b*4096+l]*lnw[c0+r] + lnb[c0+r];
            abt[r][cc] = LD(&bc[((size_t)lb*192 + r)*4096 + l]);
        }
        __syncthreads();
        for (int l4=0;l4<16;l4++){
            float x0=xt[lane][l4*4], x1v=xt[lane][l4*4+1], x2v=xt[lane][l4*4+2], x3v=xt[lane][l4*4+3];
            #pragma unroll
            for (int i=0;i<16;i++){
                float4 a = *(const float4*)&abt[sg*16+i][l4*4];
                acc[i] += x0*a.x + x1v*a.y + x2v*a.z + x3v*a.w;
            }
        }
    }
    #pragma unroll
    for (int i=0;i<16;i++)
        atomicAdd(&h[((size_t)lb*256 + c0 + lane)*64 + sg*16 + i], acc[i]);
}

// ---------- hz = hz_w(512,256) @ h ----------
__global__ __launch_bounds__(256) void hz_gemm(const float* __restrict__ h, const float* __restrict__ w,
                                               float* __restrict__ hz)
{
    __shared__ float ht[256][64];
    int blk = blockIdx.x; int lb = blk>>3; int o0 = (blk&7)*64;
    int tid = threadIdx.x;
    const float* hp = h + (size_t)lb*16384;
    for (int i=tid;i<16384;i+=256) ht[i>>6][i&63]=hp[i];
    __syncthreads();
    int lane=tid&63, g=tid>>6;
    for (int i4=0;i4<4;i4++){
        int ol = g*16 + i4*4;
        const float* r0 = w + (size_t)(o0+ol)*256;
        const float *r1=r0+256, *r2=r0+512, *r3=r0+768;
        float d0=0.f,d1=0.f,d2=0.f,d3=0.f;
        #pragma unroll 8
        for (int c4=0;c4<64;c4++){
            float x0=ht[c4*4][lane],x1v=ht[c4*4+1][lane],x2v=ht[c4*4+2][lane],x3v=ht[c4*4+3][lane];
            float4 a0=((const float4*)r0)[c4],a1=((const float4*)r1)[c4];
            float4 a2=((const float4*)r2)[c4],a3=((const float4*)r3)[c4];
            d0 += a0.x*x0+a0.y*x1v+a0.z*x2v+a0.w*x3v;
            d1 += a1.x*x0+a1.y*x1v+a1.z*x2v+a1.w*x3v;
            d2 += a2.x*x0+a2.y*x1v+a2.z*x2v+a2.w*x3v;
            d3 += a3.x*x0+a3.y*x1v+a3.z*x2v+a3.w*x3v;
        }
        size_t base = ((size_t)lb*512 + o0 + ol)*64 + lane;
        hz[base]=d0; hz[base+64]=d1; hz[base+128]=d2; hz[base+192]=d3;
    }
}

// ---------- hg = hh*(silu(z)+D) ----------
__global__ void gate_k(const float* __restrict__ hz, float* __restrict__ hg, const float* __restrict__ Dp)
{
    int i = blockIdx.x*256 + threadIdx.x;
    int lb = i >> 14;
    int r = i & 16383;
    const float* hp = hz + (size_t)lb*32768;
    float hh = hp[r], z = hp[16384 + r];
    float sil = z / (1.f + expf(-z));
    hg[i] = hh * (sil + Dp[0]);
}

// ---------- hout = out_w(256,256) @ hg ; also write f32 output copy ----------
__global__ __launch_bounds__(256) void out_gemm(const float* __restrict__ hg, const float* __restrict__ w,
        float* __restrict__ hout, float* __restrict__ hout_out, int b0)
{
    __shared__ float ht[256][64];
    int blk = blockIdx.x; int lb = blk>>2; int b = b0 + lb; int o0 = (blk&3)*64;
    int tid = threadIdx.x;
    const float* hp = hg + (size_t)lb*16384;
    for (int i=tid;i<16384;i+=256) ht[i>>6][i&63]=hp[i];
    __syncthreads();
    int lane=tid&63, g=tid>>6;
    for (int i4=0;i4<4;i4++){
        int ol = g*16 + i4*4;
        const float* r0 = w + (size_t)(o0+ol)*256;
        const float *r1=r0+256, *r2=r0+512, *r3=r0+768;
        float d0=0.f,d1=0.f,d2=0.f,d3=0.f;
        #pragma unroll 8
        for (int c4=0;c4<64;c4++){
            float x0=ht[c4*4][lane],x1v=ht[c4*4+1][lane],x2v=ht[c4*4+2][lane],x3v=ht[c4*4+3][lane];
            float4 a0=((const float4*)r0)[c4],a1=((const float4*)r1)[c4];
            float4 a2=((const float4*)r2)[c4],a3=((const float4*)r3)[c4];
            d0 += a0.x*x0+a0.y*x1v+a0.z*x2v+a0.w*x3v;
            d1 += a1.x*x0+a1.y*x1v+a1.z*x2v+a1.w*x3v;
            d2 += a2.x*x0+a2.y*x1v+a2.z*x2v+a2.w*x3v;
            d3 += a3.x*x0+a3.y*x1v+a3.z*x2v+a3.w*x3v;
        }
        size_t lbase = ((size_t)lb*256 + o0 + ol)*64 + lane;
        hout[lbase]=d0; hout[lbase+64]=d1; hout[lbase+128]=d2; hout[lbase+192]=d3;
        size_t gbase = ((size_t)b*256 + o0 + ol)*64 + lane;
        hout_out[gbase]=d0; hout_out[gbase+64]=d1;
        hout_out[gbase+128]=d2; hout_out[gbase+192]=d3;
    }
}

// ---------- y = hout @ Cm ; x2 = (1-a1)*x1 + a1*y  (in place on x1) ----------
template<typename TS>
__global__ __launch_bounds__(256) void y_blend(const float* __restrict__ hout, const TS* __restrict__ bc,
        float* __restrict__ x1, const float* __restrict__ alpha, int b0)
{
    __shared__ float ho[256][64];
    __shared__ float cm[64][64];
    int blk = blockIdx.x; int lb = blk>>6; int b = b0 + lb; int l0 = (blk&63)<<6;
    int tid = threadIdx.x;
    const float* hp = hout + (size_t)lb*16384;
    for (int i=tid;i<16384;i+=256) ho[i>>6][i&63]=hp[i];
    const TS* cp = bc + ((size_t)lb*192 + 64)*4096 + l0;
    for (int i=tid;i<4096;i+=256){ int s=i>>6, px=i&63; cm[s][px] = LD(&cp[(size_t)s*4096+px]); }
    __syncthreads();
    int lane=tid&63, g=tid>>6;
    float acc[64];
    #pragma unroll
    for (int i=0;i<64;i++) acc[i]=0.f;
    for (int s=0;s<64;s++){
        float cv = cm[s][lane];
        #pragma unroll
        for (int i=0;i<64;i++) acc[i] += ho[g*64+i][s]*cv;
    }
    float* xp = x1 + (size_t)b*256*4096 + l0;
    #pragma unroll
    for (int i=0;i<64;i++){
        int c = g*64+i;
        float av = sigm(alpha[256+c]);
        float xv = xp[(size_t)c*4096+lane];
        xp[(size_t)c*4096+lane] = (1.f-av)*xv + av*acc[i];
    }
}

// ---------- fused FFN: relu(bn1(fc1@x)) -> bn2(fc2@t) -> alpha blend (in place) ----------
__device__ __forceinline__ float bnrelu(float d, int hidx, const float* g, const float* b,
                                        const float* m, const float* v)
{
    float sc = g[hidx] * rsqrtf(v[hidx] + NEPS);
    return fmaxf((d - m[hidx])*sc + b[hidx], 0.f);
}

__global__ __launch_bounds__(256) void ffn_k(const float* __restrict__ x,
        const float* __restrict__ w1, const float* __restrict__ g1, const float* __restrict__ b1,
        const float* __restrict__ m1, const float* __restrict__ v1,
        const float* __restrict__ w2, const float* __restrict__ g2, const float* __restrict__ b2,
        const float* __restrict__ m2, const float* __restrict__ v2,
        const float* __restrict__ alpha, float* __restrict__ out)
{
    __shared__ float xt[256][64];
    __shared__ float tt[64][64];
    int blk = blockIdx.x;
    int b = blk >> 6;
    int l0 = (blk & 63) << 6;
    int tid = threadIdx.x;
    const float* xp = x + (size_t)b*256*4096 + l0;
    for (int i=tid;i<16384;i+=256){ int c=i>>6, px=i&63; xt[c][px] = xp[(size_t)c*4096+px]; }
    __syncthreads();
    int lane = tid&63, g = tid>>6;
    float acc[64];
    #pragma unroll
    for (int i=0;i<64;i++) acc[i]=0.f;
    for (int hc=0; hc<1024; hc+=64){
        __syncthreads();            // previous phase-B readers of tt done
        for (int i4=0;i4<4;i4++){
            int h0 = hc + g*16 + i4*4;
            const float* r0 = w1 + (size_t)h0*256;
            const float *r1=r0+256, *r2=r0+512, *r3=r0+768;
            float d0=0.f,d1=0.f,d2=0.f,d3=0.f;
            #pragma unroll 8
            for (int c4=0;c4<64;c4++){
                float x0=xt[c4*4][lane],x1v=xt[c4*4+1][lane],x2v=xt[c4*4+2][lane],x3v=xt[c4*4+3][lane];
                float4 a0=((const float4*)r0)[c4],a1=((const float4*)r1)[c4];
                float4 a2=((const float4*)r2)[c4],a3=((const float4*)r3)[c4];
                d0 += a0.x*x0+a0.y*x1v+a0.z*x2v+a0.w*x3v;
                d1 += a1.x*x0+a1.y*x1v+a1.z*x2v+a1.w*x3v;
                d2 += a2.x*x0+a2.y*x1v+a2.z*x2v+a2.w*x3v;
                d3 += a3.x*x0+a3.y*x1v+a3.z*x2v+a3.w*x3v;
            }
            int tl = g*16 + i4*4;
            tt[tl+0][lane] = bnrelu(d0, h0+0, g1,b1,m1,v1);
            tt[tl+1][lane] = bnrelu(d1, h0+1, g1,b1,m1,v1);
            tt[tl+2][lane] = bnrelu(d2, h0+2, g1,b1,m1,v1);
            tt[tl+3][lane] = bnrelu(d3, h0+3, g1,b1,m1,v1);
        }
        __syncthreads();
        float treg[64];
        #pragma unroll
        for (int hl=0;hl<64;hl++) treg[hl] = tt[hl][lane];
        #pragma unroll
        for (int i=0;i<64;i++){
            const float* wr = w2 + (size_t)(g*64+i)*1024 + hc;
            float d = acc[i];
            #pragma unroll
            for (int h4=0;h4<16;h4++){
                float4 u = ((const float4*)wr)[h4];
                d += u.x*treg[h4*4] + u.y*treg[h4*4+1]
                   + u.z*treg[h4*4+2] + u.w*treg[h4*4+3];
            }
            acc[i] = d;
        }
    }
    float* op = out + (size_t)b*256*4096 + l0;
    #pragma unroll
    for (int i=0;i<64;i++){
        int c = g*64+i;
        float sc = g2[c] * rsqrtf(v2[c] + NEPS);
        float t2 = (acc[i] - m2[c])*sc + b2[c];
        float av = sigm(alpha[768+c]);
        float xv = xt[c][lane];
        op[(size_t)c*4096 + lane] = (1.f-av)*xv + av*t2;
    }
}

// ---------- mixer chain for one chunk of NB batches ----------
template<typename TS>
static void run_mixer(float* x1, float* meanp, float* invp,
                      const float* lnw, const float* lnb, const float* bcdtw,
                      const float* dwmw, const float* Ap, const float* hzw,
                      const float* outw, const float* Dp, const float* alpha,
                      float* hout_out, char* cbase, int NB, hipStream_t stream)
{
    TS* bc = (TS*)cbase;
    float* h  = (float*)(cbase + (size_t)NB*192*4096*sizeof(TS));
    float* hz = h  + (size_t)NB*16384;
    float* hg = hz + (size_t)NB*32768;
    float* ho = hg + (size_t)NB*16384;
    for (int b0 = 0; b0 < 32; b0 += NB) {
        bcdt_gemm<TS><<<NB*64,256,0,stream>>>(x1, meanp, invp, lnw, lnb, bcdtw, bc, b0);
        dwconv_plain<TS><<<NB*192,256,0,stream>>>(bc, dwmw);
        softmax_ab<TS><<<NB*64,256,0,stream>>>(bc, Ap);
        hipMemsetAsync(h, 0, (size_t)NB*16384*4, stream);
        h_gemm<TS><<<NB*32,256,0,stream>>>(x1, meanp, invp, lnw, lnb, bc, h, b0);
        hz_gemm<<<NB*8,256,0,stream>>>(h, hzw, hz);
        gate_k<<<NB*64,256,0,stream>>>(hz, hg, Dp);
        out_gemm<<<NB*4,256,0,stream>>>(hg, outw, ho, hout_out, b0);
        y_blend<TS><<<NB*64,256,0,stream>>>(ho, bc, x1, alpha, b0);
    }
}

extern "C" void kernel_launch(void* const* d_in, const int* in_sizes, int n_in,
                              void* d_out, int out_size, void* d_ws, size_t ws_size,
                              hipStream_t stream)
{
    (void)in_sizes; (void)n_in; (void)out_size;
    const float* x     = (const float*)d_in[0];
    const float* dw1w  = (const float*)d_in[1];
    const float* dw1g  = (const float*)d_in[2];
    const float* dw1b  = (const float*)d_in[3];
    const float* dw1m  = (const float*)d_in[4];
    const float* dw1v  = (const float*)d_in[5];
    const float* lnw   = (const float*)d_in[6];
    const float* lnb   = (const float*)d_in[7];
    const float* bcdtw = (const float*)d_in[8];
    const float* dwmw  = (const float*)d_in[9];
    const float* Ap    = (const float*)d_in[10];
    const float* hzw   = (const float*)d_in[11];
    const float* outw  = (const float*)d_in[12];
    const float* Dp    = (const float*)d_in[13];
    const float* dw2w  = (const float*)d_in[14];
    const float* dw2g  = (const float*)d_in[15];
    const float* dw2b  = (const float*)d_in[16];
    const float* dw2m  = (const float*)d_in[17];
    const float* dw2v  = (const float*)d_in[18];
    const float* f1w   = (const float*)d_in[19];
    const float* f1g   = (const float*)d_in[20];
    const float* f1b   = (const float*)d_in[21];
    const float* f1m   = (const float*)d_in[22];
    const float* f1v   = (const float*)d_in[23];
    const float* f2w   = (const float*)d_in[24];
    const float* f2g   = (const float*)d_in[25];
    const float* f2b   = (const float*)d_in[26];
    const float* f2m   = (const float*)d_in[27];
    const float* f2v   = (const float*)d_in[28];
    const float* alpha = (const float*)d_in[29];

    const size_t nx = (size_t)32*256*4096;
    float* x1 = (float*)d_out;          // x1 lives in d_out's x region (we own it, fully rewritten)
    float* hout_out = x1 + nx;          // hout output region (f32)

    char* ws = (char*)d_ws;
    float* meanp = (float*)ws;          // 131072 f32 = 512 KB
    float* invp  = meanp + 131072;      // 512 KB
    char* cbase  = ws + (size_t)1048576;
    size_t avail = ws_size > 1048576 ? ws_size - 1048576 : 0;

    // per-b chunk footprint: bc (f32 3,145,728 | bf16 1,572,864) + h/hz/hg/ho 327,680
    const size_t perbF = (size_t)192*4096*4 + 327680;   // 3,473,408
    const size_t perbH = (size_t)192*4096*2 + 327680;   // 1,900,544

    dwconv_bn_blend<<<8192,256,0,stream>>>(x, x1, dw1w,dw1g,dw1b,dw1m,dw1v, alpha, 0);
    ln_stats<<<512,256,0,stream>>>(x1, meanp, invp);

    int NBf = 0, NBh = 0;
    for (int nb = 32; nb >= 1; nb >>= 1) { if (!NBf && avail >= nb*perbF) NBf = nb;
                                           if (!NBh && avail >= nb*perbH) NBh = nb; }
    if (NBf >= NBh && NBf > 0)
        run_mixer<float>(x1, meanp, invp, lnw, lnb, bcdtw, dwmw, Ap, hzw, outw, Dp, alpha,
                         hout_out, cbase, NBf, stream);
    else
        run_mixer<bf16>(x1, meanp, invp, lnw, lnb, bcdtw, dwmw, Ap, hzw, outw, Dp, alpha,
                        hout_out, cbase, NBh > 0 ? NBh : 1, stream);

    dwconv_bn_blend<<<8192,256,0,stream>>>(x1, x1, dw2w,dw2g,dw2b,dw2m,dw2v, alpha, 2);
    ffn_k<<<2048,256,0,stream>>>(x1, f1w,f1g,f1b,f1m,f1v, f2w,f2g,f2b,f2m,f2v, alpha, x1);
}

// Round 4
// 1736.230 us; speedup vs baseline: 5.3283x; 5.3283x over previous
//
#include <hip/hip_runtime.h>
#include <hip/hip_bf16.h>

typedef __hip_bfloat16 bf16;
typedef __attribute__((ext_vector_type(8))) short bf16x8;
typedef __attribute__((ext_vector_type(4))) float f32x4;

// ---------- helpers ----------
__device__ __forceinline__ float LD(const float* p){ return *p; }
__device__ __forceinline__ float LD(const bf16* p){ return __bfloat162float(*p); }
__device__ __forceinline__ void ST(float* p, float v){ *p = v; }
__device__ __forceinline__ void ST(bf16* p, float v){ *p = __float2bfloat16(v); }
__device__ __forceinline__ float sigm(float v){ return 1.f/(1.f + expf(-v)); }
__device__ __forceinline__ ushort f2b(float f){            // RNE f32->bf16 bits
    unsigned u = __float_as_uint(f);
    return (ushort)((u + 0x7fffu + ((u>>16)&1u)) >> 16);
}

#define NEPS 1e-5f

// ---------- depthwise 3x3 + BN + alpha blend (one block per (b,ch) plane) ----------
__global__ __launch_bounds__(256) void dwconv_bn_blend(
        const float* __restrict__ xin, float* __restrict__ xout,
        const float* __restrict__ w, const float* __restrict__ gg, const float* __restrict__ bb,
        const float* __restrict__ mm, const float* __restrict__ vv,
        const float* __restrict__ alpha, int arow)
{
    __shared__ float tile[66*66];
    int blk = blockIdx.x;
    int ch = blk & 255;
    const float* xp = xin + (size_t)blk*4096;
    float* op = xout + (size_t)blk*4096;
    int tid = threadIdx.x;
    for (int i = tid; i < 66*66; i += 256) {
        int r = i/66, c = i%66;
        int gr = r-1, gc = c-1;
        float val = 0.f;
        if (gr >= 0 && gr < 64 && gc >= 0 && gc < 64) val = xp[gr*64+gc];
        tile[i] = val;
    }
    __syncthreads();
    float wv[9];
    #pragma unroll
    for (int k=0;k<9;k++) wv[k] = w[ch*9+k];
    float sc = gg[ch] * rsqrtf(vv[ch] + NEPS);
    float mv = mm[ch], bv = bb[ch];
    float av = sigm(alpha[arow*256+ch]);
    for (int p = tid; p < 4096; p += 256) {
        int r = p>>6, c = p&63;
        float a = 0.f;
        #pragma unroll
        for (int dr=0;dr<3;dr++)
            #pragma unroll
            for (int dc=0;dc<3;dc++)
                a += wv[dr*3+dc]*tile[(r+dr)*66 + (c+dc)];
        float bn = (a - mv)*sc + bv;
        float xv = tile[(r+1)*66 + (c+1)];
        op[p] = (1.f-av)*xv + av*bn;
    }
}

// ---------- LayerNorm stats over channel dim: mean[b,l], inv[b,l] ----------
__global__ __launch_bounds__(256) void ln_stats(const float* __restrict__ x1,
        float* __restrict__ meanp, float* __restrict__ invp)
{
    int blk = blockIdx.x;
    int b = blk >> 4;
    int l = ((blk & 15) << 8) + threadIdx.x;
    const float* xp = x1 + (size_t)b*256*4096 + l;
    float mean = 0.f, m2 = 0.f;
    for (int c=0;c<256;c++){ float v = xp[(size_t)c*4096]; mean += v; m2 += v*v; }
    mean *= (1.f/256.f); m2 *= (1.f/256.f);
    meanp[b*4096 + l] = mean;
    invp[b*4096 + l] = rsqrtf(m2 - mean*mean + NEPS);
}

// ---------- prep: weights->bf16, fold BN ----------
__global__ __launch_bounds__(256) void prep_k(
        const float* __restrict__ f1w, const float* __restrict__ f2w,
        const float* __restrict__ g1, const float* __restrict__ b1,
        const float* __restrict__ m1, const float* __restrict__ v1,
        const float* __restrict__ g2, const float* __restrict__ b2,
        const float* __restrict__ m2, const float* __restrict__ v2,
        ushort* __restrict__ w1bf, ushort* __restrict__ w2bf,
        float* __restrict__ sc1, float* __restrict__ sb1,
        float* __restrict__ sc2, float* __restrict__ sb2)
{
    int i = blockIdx.x*256 + threadIdx.x;
    if (i < 262144) {
        w1bf[i] = f2b(f1w[i]);
        w2bf[i] = f2b(f2w[i]);
    }
    if (i < 1024) { float s = g1[i]*rsqrtf(v1[i]+NEPS); sc1[i]=s; sb1[i]=b1[i]-m1[i]*s; }
    if (i < 256)  { float s = g2[i]*rsqrtf(v2[i]+NEPS); sc2[i]=s; sb2[i]=b2[i]-m2[i]*s; }
}

// ---------- bc_dt = bcdt_w(192,256) @ LN(x1) : block = (lb, 64-px tile) ----------
template<typename TS>
__global__ __launch_bounds__(256) void bcdt_gemm(const float* __restrict__ x1,
        const float* __restrict__ meanp, const float* __restrict__ invp,
        const float* __restrict__ lnw, const float* __restrict__ lnb,
        const float* __restrict__ w, TS* __restrict__ bc, int b0)
{
    __shared__ float xt[256][64];
    int blk = blockIdx.x;
    int lb = blk >> 6;
    int b = b0 + lb;
    int l0 = (blk & 63) << 6;
    int tid = threadIdx.x;
    const float* xp = x1 + (size_t)b*256*4096 + l0;
    const float* mp = meanp + b*4096 + l0;
    const float* ip = invp + b*4096 + l0;
    for (int i=tid; i<256*64; i+=256){
        int c=i>>6, px=i&63;
        float v = xp[(size_t)c*4096+px];
        xt[c][px] = (v - mp[px])*ip[px]*lnw[c] + lnb[c];
    }
    __syncthreads();
    int lane = tid&63, g = tid>>6;
    TS* op = bc + (size_t)lb*192*4096 + l0;
    for (int i4=0; i4<12; i4++){
        int o = g*48 + i4*4;
        const float* r0 = w + (size_t)o*256;
        const float *r1 = r0+256, *r2 = r0+512, *r3 = r0+768;
        float d0=0.f,d1=0.f,d2=0.f,d3=0.f;
        #pragma unroll 8
        for (int c4=0;c4<64;c4++){
            float x0=xt[c4*4][lane], x1v=xt[c4*4+1][lane], x2v=xt[c4*4+2][lane], x3v=xt[c4*4+3][lane];
            float4 a0=((const float4*)r0)[c4], a1=((const float4*)r1)[c4];
            float4 a2=((const float4*)r2)[c4], a3=((const float4*)r3)[c4];
            d0 += a0.x*x0 + a0.y*x1v + a0.z*x2v + a0.w*x3v;
            d1 += a1.x*x0 + a1.y*x1v + a1.z*x2v + a1.w*x3v;
            d2 += a2.x*x0 + a2.y*x1v + a2.z*x2v + a2.w*x3v;
            d3 += a3.x*x0 + a3.y*x1v + a3.z*x2v + a3.w*x3v;
        }
        ST(&op[(size_t)(o+0)*4096 + lane], d0);
        ST(&op[(size_t)(o+1)*4096 + lane], d1);
        ST(&op[(size_t)(o+2)*4096 + lane], d2);
        ST(&op[(size_t)(o+3)*4096 + lane], d3);
    }
}

// ---------- plain depthwise 3x3, in-place (192 channels per batch) ----------
template<typename TS>
__global__ __launch_bounds__(256) void dwconv_plain(TS* __restrict__ data, const float* __restrict__ w)
{
    __shared__ float tile[66*66];
    int blk = blockIdx.x;
    int ch = blk % 192;
    TS* xp = data + (size_t)blk*4096;
    int tid = threadIdx.x;
    for (int i = tid; i < 66*66; i += 256) {
        int r = i/66, c = i%66;
        int gr = r-1, gc = c-1;
        float val = 0.f;
        if (gr >= 0 && gr < 64 && gc >= 0 && gc < 64) val = LD(&xp[gr*64+gc]);
        tile[i] = val;
    }
    __syncthreads();
    float wv[9];
    #pragma unroll
    for (int k=0;k<9;k++) wv[k] = w[ch*9+k];
    for (int p = tid; p < 4096; p += 256) {
        int r = p>>6, c = p&63;
        float a = 0.f;
        #pragma unroll
        for (int dr=0;dr<3;dr++)
            #pragma unroll
            for (int dc=0;dc<3;dc++)
                a += wv[dr*3+dc]*tile[(r+dr)*66 + (c+dc)];
        ST(&xp[p], a);
    }
}

// ---------- softmax over L (per (lb,s)) and AB = Am*Bm in place over Bm rows ----------
template<typename TS>
__global__ __launch_bounds__(256) void softmax_ab(TS* __restrict__ bc, const float* __restrict__ A)
{
    __shared__ float red[8];
    int blk = blockIdx.x;
    int lb = blk >> 6;
    int s = blk & 63;
    TS* dtp = bc + ((size_t)lb*192 + 128 + s)*4096;
    TS* bmp = bc + ((size_t)lb*192 + s)*4096;
    int tid = threadIdx.x;
    float Av = A[s];
    float vals[16];
    float mx = -1e30f;
    #pragma unroll
    for (int i=0;i<16;i++){ vals[i] = LD(&dtp[i*256+tid]) + Av; mx = fmaxf(mx, vals[i]); }
    #pragma unroll
    for (int o=32;o>0;o>>=1) mx = fmaxf(mx, __shfl_down(mx, o));
    int lane = tid & 63, wid = tid >> 6;
    if (lane == 0) red[wid] = mx;
    __syncthreads();
    if (tid == 0) red[4] = fmaxf(fmaxf(red[0],red[1]), fmaxf(red[2],red[3]));
    __syncthreads();
    mx = red[4];
    float sum = 0.f;
    #pragma unroll
    for (int i=0;i<16;i++){ vals[i] = expf(vals[i]-mx); sum += vals[i]; }
    #pragma unroll
    for (int o=32;o>0;o>>=1) sum += __shfl_down(sum, o);
    if (lane == 0) red[wid] = sum;
    __syncthreads();
    if (tid == 0) red[5] = red[0]+red[1]+red[2]+red[3];
    __syncthreads();
    float inv = 1.f/red[5];
    #pragma unroll
    for (int i=0;i<16;i++){
        float ab = vals[i]*inv*LD(&bmp[i*256+tid]);
        ST(&bmp[i*256+tid], ab);
    }
}

// ---------- h[lb,c,s] = sum_l LN(x1)[b,c,l]*AB[lb,s,l]  (split-L, atomic acc) ----------
template<typename TS>
__global__ __launch_bounds__(256) void h_gemm(const float* __restrict__ x1,
        const float* __restrict__ meanp, const float* __restrict__ invp,
        const float* __restrict__ lnw, const float* __restrict__ lnb,
        const TS* __restrict__ bc, float* __restrict__ h, int b0)
{
    __shared__ float xt[64][65];
    __shared__ float abt[64][64];
    int blk = blockIdx.x;
    int lb = blk >> 5;
    int b = b0 + lb;
    int ct = (blk >> 3) & 3;
    int ls = blk & 7;
    int c0 = ct*64;
    int tid = threadIdx.x;
    int lane = tid & 63, sg = tid >> 6;
    float acc[16];
    #pragma unroll
    for (int i=0;i<16;i++) acc[i]=0.f;
    for (int lc=0; lc<8; lc++){
        int lbase = ls*512 + lc*64;
        __syncthreads();
        for (int i=tid;i<4096;i+=256){
            int r=i>>6, cc=i&63;
            int l = lbase + cc;
            float v = x1[((size_t)b*256 + c0 + r)*4096 + l];
            xt[r][cc]  = (v - meanp[b*4096+l])*invp[b*4096+l]*lnw[c0+r] + lnb[c0+r];
            abt[r][cc] = LD(&bc[((size_t)lb*192 + r)*4096 + l]);
        }
        __syncthreads();
        for (int l4=0;l4<16;l4++){
            float x0=xt[lane][l4*4], x1v=xt[lane][l4*4+1], x2v=xt[lane][l4*4+2], x3v=xt[lane][l4*4+3];
            #pragma unroll
            for (int i=0;i<16;i++){
                float4 a = *(const float4*)&abt[sg*16+i][l4*4];
                acc[i] += x0*a.x + x1v*a.y + x2v*a.z + x3v*a.w;
            }
        }
    }
    #pragma unroll
    for (int i=0;i<16;i++)
        atomicAdd(&h[((size_t)lb*256 + c0 + lane)*64 + sg*16 + i], acc[i]);
}

// ---------- hz = hz_w(512,256) @ h ----------
__global__ __launch_bounds__(256) void hz_gemm(const float* __restrict__ h, const float* __restrict__ w,
                                               float* __restrict__ hz)
{
    __shared__ float ht[256][64];
    int blk = blockIdx.x; int lb = blk>>3; int o0 = (blk&7)*64;
    int tid = threadIdx.x;
    const float* hp = h + (size_t)lb*16384;
    for (int i=tid;i<16384;i+=256) ht[i>>6][i&63]=hp[i];
    __syncthreads();
    int lane=tid&63, g=tid>>6;
    for (int i4=0;i4<4;i4++){
        int ol = g*16 + i4*4;
        const float* r0 = w + (size_t)(o0+ol)*256;
        const float *r1=r0+256, *r2=r0+512, *r3=r0+768;
        float d0=0.f,d1=0.f,d2=0.f,d3=0.f;
        #pragma unroll 8
        for (int c4=0;c4<64;c4++){
            float x0=ht[c4*4][lane],x1v=ht[c4*4+1][lane],x2v=ht[c4*4+2][lane],x3v=ht[c4*4+3][lane];
            float4 a0=((const float4*)r0)[c4],a1=((const float4*)r1)[c4];
            float4 a2=((const float4*)r2)[c4],a3=((const float4*)r3)[c4];
            d0 += a0.x*x0+a0.y*x1v+a0.z*x2v+a0.w*x3v;
            d1 += a1.x*x0+a1.y*x1v+a1.z*x2v+a1.w*x3v;
            d2 += a2.x*x0+a2.y*x1v+a2.z*x2v+a2.w*x3v;
            d3 += a3.x*x0+a3.y*x1v+a3.z*x2v+a3.w*x3v;
        }
        size_t base = ((size_t)lb*512 + o0 + ol)*64 + lane;
        hz[base]=d0; hz[base+64]=d1; hz[base+128]=d2; hz[base+192]=d3;
    }
}

// ---------- hg = hh*(silu(z)+D) ----------
__global__ void gate_k(const float* __restrict__ hz, float* __restrict__ hg, const float* __restrict__ Dp)
{
    int i = blockIdx.x*256 + threadIdx.x;
    int lb = i >> 14;
    int r = i & 16383;
    const float* hp = hz + (size_t)lb*32768;
    float hh = hp[r], z = hp[16384 + r];
    float sil = z / (1.f + expf(-z));
    hg[i] = hh * (sil + Dp[0]);
}

// ---------- hout = out_w(256,256) @ hg ; also write f32 output copy ----------
__global__ __launch_bounds__(256) void out_gemm(const float* __restrict__ hg, const float* __restrict__ w,
        float* __restrict__ hout, float* __restrict__ hout_out, int b0)
{
    __shared__ float ht[256][64];
    int blk = blockIdx.x; int lb = blk>>2; int b = b0 + lb; int o0 = (blk&3)*64;
    int tid = threadIdx.x;
    const float* hp = hg + (size_t)lb*16384;
    for (int i=tid;i<16384;i+=256) ht[i>>6][i&63]=hp[i];
    __syncthreads();
    int lane=tid&63, g=tid>>6;
    for (int i4=0;i4<4;i4++){
        int ol = g*16 + i4*4;
        const float* r0 = w + (size_t)(o0+ol)*256;
        const float *r1=r0+256, *r2=r0+512, *r3=r0+768;
        float d0=0.f,d1=0.f,d2=0.f,d3=0.f;
        #pragma unroll 8
        for (int c4=0;c4<64;c4++){
            float x0=ht[c4*4][lane],x1v=ht[c4*4+1][lane],x2v=ht[c4*4+2][lane],x3v=ht[c4*4+3][lane];
            float4 a0=((const float4*)r0)[c4],a1=((const float4*)r1)[c4];
            float4 a2=((const float4*)r2)[c4],a3=((const float4*)r3)[c4];
            d0 += a0.x*x0+a0.y*x1v+a0.z*x2v+a0.w*x3v;
            d1 += a1.x*x0+a1.y*x1v+a1.z*x2v+a1.w*x3v;
            d2 += a2.x*x0+a2.y*x1v+a2.z*x2v+a2.w*x3v;
            d3 += a3.x*x0+a3.y*x1v+a3.z*x2v+a3.w*x3v;
        }
        size_t lbase = ((size_t)lb*256 + o0 + ol)*64 + lane;
        hout[lbase]=d0; hout[lbase+64]=d1; hout[lbase+128]=d2; hout[lbase+192]=d3;
        size_t gbase = ((size_t)b*256 + o0 + ol)*64 + lane;
        hout_out[gbase]=d0; hout_out[gbase+64]=d1;
        hout_out[gbase+128]=d2; hout_out[gbase+192]=d3;
    }
}

// ---------- y = hout @ Cm ; x2 = (1-a1)*x1 + a1*y  (in place on x1) ----------
template<typename TS>
__global__ __launch_bounds__(256) void y_blend(const float* __restrict__ hout, const TS* __restrict__ bc,
        float* __restrict__ x1, const float* __restrict__ alpha, int b0)
{
    __shared__ float ho[256][64];
    __shared__ float cm[64][64];
    int blk = blockIdx.x; int lb = blk>>6; int b = b0 + lb; int l0 = (blk&63)<<6;
    int tid = threadIdx.x;
    const float* hp = hout + (size_t)lb*16384;
    for (int i=tid;i<16384;i+=256) ho[i>>6][i&63]=hp[i];
    const TS* cp = bc + ((size_t)lb*192 + 64)*4096 + l0;
    for (int i=tid;i<4096;i+=256){ int s=i>>6, px=i&63; cm[s][px] = LD(&cp[(size_t)s*4096+px]); }
    __syncthreads();
    int lane=tid&63, g=tid>>6;
    float acc[64];
    #pragma unroll
    for (int i=0;i<64;i++) acc[i]=0.f;
    for (int s=0;s<64;s++){
        float cv = cm[s][lane];
        #pragma unroll
        for (int i=0;i<64;i++) acc[i] += ho[g*64+i][s]*cv;
    }
    float* xp = x1 + (size_t)b*256*4096 + l0;
    #pragma unroll
    for (int i=0;i<64;i++){
        int c = g*64+i;
        float av = sigm(alpha[256+c]);
        float xv = xp[(size_t)c*4096+lane];
        xp[(size_t)c*4096+lane] = (1.f-av)*xv + av*acc[i];
    }
}

// ---------- MFMA FFN: relu(bn1(fc1@x)) -> bn2(fc2@t) -> alpha blend, in place ----------
// Block = (b, 64-px tile), 4 waves. LDS: Xs [px][c] bf16 swizzled (32KB) + Ts [px][h] (16KB).
// Fragment layout (m89/m92): A/B lane holds idx (l&15) + 8 contiguous K at (l>>4)*8;
// C/D: col = l&15, row = (l>>4)*4 + r.
__global__ __launch_bounds__(256) void ffn_mfma(
        const float* __restrict__ x,
        const ushort* __restrict__ w1bf,  // [1024][256]
        const ushort* __restrict__ w2bf,  // [256][1024]
        const float* __restrict__ sc1, const float* __restrict__ sb1,
        const float* __restrict__ sc2, const float* __restrict__ sb2,
        const float* __restrict__ alpha,
        float* __restrict__ out)
{
    __shared__ __align__(16) ushort Xs[64*256];  // [px][c] bf16, 16B-block XOR swizzle
    __shared__ __align__(16) ushort Ts[64*128];  // [px][h_local] bf16, swizzled
    int blk = blockIdx.x;
    int b = blk >> 6, l0 = (blk & 63) << 6;
    int tid = threadIdx.x, lane = tid & 63, w = tid >> 6;
    const float* xp = x + (size_t)b*256*4096 + l0;

    // stage X tile: thread owns px=lane; each wave covers 8-c chunks stride-32
    for (int cc = w*8; cc < 256; cc += 32) {
        float v[8];
        #pragma unroll
        for (int j=0;j<8;j++) v[j] = xp[(size_t)(cc+j)*4096 + lane];
        uint4 pk;
        pk.x = (uint)f2b(v[0]) | ((uint)f2b(v[1])<<16);
        pk.y = (uint)f2b(v[2]) | ((uint)f2b(v[3])<<16);
        pk.z = (uint)f2b(v[4]) | ((uint)f2b(v[5])<<16);
        pk.w = (uint)f2b(v[6]) | ((uint)f2b(v[7])<<16);
        int g = (cc>>3) ^ (lane&7);
        *(uint4*)&Xs[lane*256 + g*8] = pk;
    }
    __syncthreads();

    f32x4 zero4 = {0.f,0.f,0.f,0.f};
    f32x4 acc2[4][4];
    #pragma unroll
    for (int m=0;m<4;m++)
        #pragma unroll
        for (int f=0;f<4;f++) acc2[m][f] = zero4;

    for (int hc = 0; hc < 1024; hc += 128) {
        // ---- GEMM1: this wave's h rows [hc + w*32, +32)
        int hbase = hc + w*32;
        f32x4 c1[2][4];
        #pragma unroll
        for (int m=0;m<2;m++)
            #pragma unroll
            for (int f=0;f<4;f++) c1[m][f] = zero4;
        for (int ks = 0; ks < 8; ks++) {
            bf16x8 afr[2];
            #pragma unroll
            for (int m=0;m<2;m++)
                afr[m] = *(const bf16x8*)&w1bf[(size_t)(hbase + m*16 + (lane&15))*256
                                               + ks*32 + (lane>>4)*8];
            #pragma unroll
            for (int f=0;f<4;f++){
                int px = f*16 + (lane&15);
                int g = (ks*4 + (lane>>4)) ^ (px&7);
                bf16x8 bfr = *(const bf16x8*)&Xs[px*256 + g*8];
                #pragma unroll
                for (int m=0;m<2;m++)
                    c1[m][f] = __builtin_amdgcn_mfma_f32_16x16x32_bf16(afr[m], bfr, c1[m][f], 0,0,0);
            }
        }
        __syncthreads();   // prev GEMM2 readers of Ts done
        // ---- BN1 + ReLU -> Ts (bf16, swizzled)
        #pragma unroll
        for (int m=0;m<2;m++){
            #pragma unroll
            for (int r=0;r<4;r++){
                int h = hbase + m*16 + (lane>>4)*4 + r;
                float s1 = sc1[h], bb1 = sb1[h];
                int hl = h - hc;   // 0..127
                #pragma unroll
                for (int f=0;f<4;f++){
                    int px = f*16 + (lane&15);
                    float t = fmaxf(c1[m][f][r]*s1 + bb1, 0.f);
                    int g = (hl>>3) ^ (px&7);
                    Ts[px*128 + g*8 + (hl&7)] = f2b(t);
                }
            }
        }
        __syncthreads();
        // ---- GEMM2: acc2 += W2[w*64.., hc..+128] @ Ts
        int c0 = w*64;
        for (int ks = 0; ks < 4; ks++) {
            bf16x8 afr[4];
            #pragma unroll
            for (int m=0;m<4;m++)
                afr[m] = *(const bf16x8*)&w2bf[(size_t)(c0 + m*16 + (lane&15))*1024
                                               + hc + ks*32 + (lane>>4)*8];
            #pragma unroll
            for (int f=0;f<4;f++){
                int px = f*16 + (lane&15);
                int hl = ks*32 + (lane>>4)*8;
                int g = (hl>>3) ^ (px&7);
                bf16x8 bfr = *(const bf16x8*)&Ts[px*128 + g*8];
                #pragma unroll
                for (int m=0;m<4;m++)
                    acc2[m][f] = __builtin_amdgcn_mfma_f32_16x16x32_bf16(afr[m], bfr, acc2[m][f], 0,0,0);
            }
        }
    }

    // ---- epilogue: out = (1-a)*x + a*(acc*sc2 + sb2), in place
    float* op = out + (size_t)b*256*4096 + l0;
    int c0 = w*64;
    #pragma unroll
    for (int m=0;m<4;m++){
        #pragma unroll
        for (int r=0;r<4;r++){
            int c = c0 + m*16 + (lane>>4)*4 + r;
            float a = sigm(alpha[768+c]);
            float s2 = sc2[c], bb2 = sb2[c];
            #pragma unroll
            for (int f=0;f<4;f++){
                int px = f*16 + (lane&15);
                float t2 = acc2[m][f][r]*s2 + bb2;
                float xv = xp[(size_t)c*4096 + px];
                op[(size_t)c*4096 + px] = (1.f-a)*xv + a*t2;
            }
        }
    }
}

// ---------- mixer chain for one chunk of NB batches ----------
template<typename TS>
static void run_mixer(float* x1, float* meanp, float* invp,
                      const float* lnw, const float* lnb, const float* bcdtw,
                      const float* dwmw, const float* Ap, const float* hzw,
                      const float* outw, const float* Dp, const float* alpha,
                      float* hout_out, char* cbase, int NB, hipStream_t stream)
{
    TS* bc = (TS*)cbase;
    float* h  = (float*)(cbase + (size_t)NB*192*4096*sizeof(TS));
    float* hz = h  + (size_t)NB*16384;
    float* hg = hz + (size_t)NB*32768;
    float* ho = hg + (size_t)NB*16384;
    for (int b0 = 0; b0 < 32; b0 += NB) {
        bcdt_gemm<TS><<<NB*64,256,0,stream>>>(x1, meanp, invp, lnw, lnb, bcdtw, bc, b0);
        dwconv_plain<TS><<<NB*192,256,0,stream>>>(bc, dwmw);
        softmax_ab<TS><<<NB*64,256,0,stream>>>(bc, Ap);
        hipMemsetAsync(h, 0, (size_t)NB*16384*4, stream);
        h_gemm<TS><<<NB*32,256,0,stream>>>(x1, meanp, invp, lnw, lnb, bc, h, b0);
        hz_gemm<<<NB*8,256,0,stream>>>(h, hzw, hz);
        gate_k<<<NB*64,256,0,stream>>>(hz, hg, Dp);
        out_gemm<<<NB*4,256,0,stream>>>(hg, outw, ho, hout_out, b0);
        y_blend<TS><<<NB*64,256,0,stream>>>(ho, bc, x1, alpha, b0);
    }
}

extern "C" void kernel_launch(void* const* d_in, const int* in_sizes, int n_in,
                              void* d_out, int out_size, void* d_ws, size_t ws_size,
                              hipStream_t stream)
{
    (void)in_sizes; (void)n_in; (void)out_size;
    const float* x     = (const float*)d_in[0];
    const float* dw1w  = (const float*)d_in[1];
    const float* dw1g  = (const float*)d_in[2];
    const float* dw1b  = (const float*)d_in[3];
    const float* dw1m  = (const float*)d_in[4];
    const float* dw1v  = (const float*)d_in[5];
    const float* lnw   = (const float*)d_in[6];
    const float* lnb   = (const float*)d_in[7];
    const float* bcdtw = (const float*)d_in[8];
    const float* dwmw  = (const float*)d_in[9];
    const float* Ap    = (const float*)d_in[10];
    const float* hzw   = (const float*)d_in[11];
    const float* outw  = (const float*)d_in[12];
    const float* Dp    = (const float*)d_in[13];
    const float* dw2w  = (const float*)d_in[14];
    const float* dw2g  = (const float*)d_in[15];
    const float* dw2b  = (const float*)d_in[16];
    const float* dw2m  = (const float*)d_in[17];
    const float* dw2v  = (const float*)d_in[18];
    const float* f1w   = (const float*)d_in[19];
    const float* f1g   = (const float*)d_in[20];
    const float* f1b   = (const float*)d_in[21];
    const float* f1m   = (const float*)d_in[22];
    const float* f1v   = (const float*)d_in[23];
    const float* f2w   = (const float*)d_in[24];
    const float* f2g   = (const float*)d_in[25];
    const float* f2b_  = (const float*)d_in[26];
    const float* f2m   = (const float*)d_in[27];
    const float* f2v   = (const float*)d_in[28];
    const float* alpha = (const float*)d_in[29];

    const size_t nx = (size_t)32*256*4096;
    float* x1 = (float*)d_out;          // x1 lives in d_out's x region
    float* hout_out = x1 + nx;          // hout output region (f32)

    char* ws = (char*)d_ws;
    float* meanp = (float*)ws;                       // 512 KB
    float* invp  = meanp + 131072;                   // 512 KB
    size_t off = 1048576;
    ushort* w1bf = (ushort*)(ws + off); off += 524288;
    ushort* w2bf = (ushort*)(ws + off); off += 524288;
    float* sc1 = (float*)(ws + off); off += 4096;
    float* sb1 = (float*)(ws + off); off += 4096;
    float* sc2 = (float*)(ws + off); off += 1024;
    float* sb2 = (float*)(ws + off); off += 1024;    // off = 2107392 (256-aligned)
    char* cbase = ws + off;
    size_t avail = ws_size > off ? ws_size - off : 0;

    const size_t perbF = (size_t)192*4096*4 + 327680;   // 3,473,408
    const size_t perbH = (size_t)192*4096*2 + 327680;   // 1,900,544

    prep_k<<<1024,256,0,stream>>>(f1w, f2w, f1g,f1b,f1m,f1v, f2g,f2b_,f2m,f2v,
                                  w1bf, w2bf, sc1, sb1, sc2, sb2);
    dwconv_bn_blend<<<8192,256,0,stream>>>(x, x1, dw1w,dw1g,dw1b,dw1m,dw1v, alpha, 0);
    ln_stats<<<512,256,0,stream>>>(x1, meanp, invp);

    int NBf = 0, NBh = 0;
    for (int nb = 32; nb >= 1; nb >>= 1) { if (!NBf && avail >= nb*perbF) NBf = nb;
                                           if (!NBh && avail >= nb*perbH) NBh = nb; }
    if (NBf >= NBh && NBf > 0)
        run_mixer<float>(x1, meanp, invp, lnw, lnb, bcdtw, dwmw, Ap, hzw, outw, Dp, alpha,
                         hout_out, cbase, NBf, stream);
    else
        run_mixer<bf16>(x1, meanp, invp, lnw, lnb, bcdtw, dwmw, Ap, hzw, outw, Dp, alpha,
                        hout_out, cbase, NBh > 0 ? NBh : 1, stream);

    dwconv_bn_blend<<<8192,256,0,stream>>>(x1, x1, dw2w,dw2g,dw2b,dw2m,dw2v, alpha, 2);
    ffn_mfma<<<2048,256,0,stream>>>(x1, w1bf, w2bf, sc1, sb1, sc2, sb2, alpha, x1);
}

// Round 5
// 734.642 us; speedup vs baseline: 12.5927x; 2.3634x over previous
//
#include <hip/hip_runtime.h>
#include <hip/hip_bf16.h>

typedef __hip_bfloat16 bf16;
typedef __attribute__((ext_vector_type(8))) short bf16x8;
typedef __attribute__((ext_vector_type(4))) float f32x4;

// ---------- helpers ----------
__device__ __forceinline__ float LD(const float* p){ return *p; }
__device__ __forceinline__ float LD(const bf16* p){ return __bfloat162float(*p); }
__device__ __forceinline__ void ST(float* p, float v){ *p = v; }
__device__ __forceinline__ void ST(bf16* p, float v){ *p = __float2bfloat16(v); }
__device__ __forceinline__ float sigm(float v){ return 1.f/(1.f + expf(-v)); }
__device__ __forceinline__ ushort f2b(float f){            // RNE f32->bf16 bits
    unsigned u = __float_as_uint(f);
    return (ushort)((u + 0x7fffu + ((u>>16)&1u)) >> 16);
}

#define NEPS 1e-5f

// ---------- depthwise 3x3 + BN + alpha blend (one block per (b,ch) plane) ----------
__global__ __launch_bounds__(256) void dwconv_bn_blend(
        const float* __restrict__ xin, float* __restrict__ xout,
        const float* __restrict__ w, const float* __restrict__ gg, const float* __restrict__ bb,
        const float* __restrict__ mm, const float* __restrict__ vv,
        const float* __restrict__ alpha, int arow)
{
    __shared__ float tile[66*66];
    int blk = blockIdx.x;
    int ch = blk & 255;
    const float* xp = xin + (size_t)blk*4096;
    float* op = xout + (size_t)blk*4096;
    int tid = threadIdx.x;
    for (int i = tid; i < 66*66; i += 256) {
        int r = i/66, c = i%66;
        int gr = r-1, gc = c-1;
        float val = 0.f;
        if (gr >= 0 && gr < 64 && gc >= 0 && gc < 64) val = xp[gr*64+gc];
        tile[i] = val;
    }
    __syncthreads();
    float wv[9];
    #pragma unroll
    for (int k=0;k<9;k++) wv[k] = w[ch*9+k];
    float sc = gg[ch] * rsqrtf(vv[ch] + NEPS);
    float mv = mm[ch], bv = bb[ch];
    float av = sigm(alpha[arow*256+ch]);
    for (int p = tid; p < 4096; p += 256) {
        int r = p>>6, c = p&63;
        float a = 0.f;
        #pragma unroll
        for (int dr=0;dr<3;dr++)
            #pragma unroll
            for (int dc=0;dc<3;dc++)
                a += wv[dr*3+dc]*tile[(r+dr)*66 + (c+dc)];
        float bn = (a - mv)*sc + bv;
        float xv = tile[(r+1)*66 + (c+1)];
        op[p] = (1.f-av)*xv + av*bn;
    }
}

// ---------- LayerNorm stats over channel dim: mean[b,l], inv[b,l] ----------
__global__ __launch_bounds__(256) void ln_stats(const float* __restrict__ x1,
        float* __restrict__ meanp, float* __restrict__ invp)
{
    int blk = blockIdx.x;
    int b = blk >> 4;
    int l = ((blk & 15) << 8) + threadIdx.x;
    const float* xp = x1 + (size_t)b*256*4096 + l;
    float mean = 0.f, m2 = 0.f;
    for (int c=0;c<256;c++){ float v = xp[(size_t)c*4096]; mean += v; m2 += v*v; }
    mean *= (1.f/256.f); m2 *= (1.f/256.f);
    meanp[b*4096 + l] = mean;
    invp[b*4096 + l] = rsqrtf(m2 - mean*mean + NEPS);
}

// ---------- prep: weights->bf16, fold BN ----------
__global__ __launch_bounds__(256) void prep_k(
        const float* __restrict__ f1w, const float* __restrict__ f2w,
        const float* __restrict__ bcdtw,
        const float* __restrict__ g1, const float* __restrict__ b1,
        const float* __restrict__ m1, const float* __restrict__ v1,
        const float* __restrict__ g2, const float* __restrict__ b2,
        const float* __restrict__ m2, const float* __restrict__ v2,
        ushort* __restrict__ w1bf, ushort* __restrict__ w2bf,
        ushort* __restrict__ wbc,
        float* __restrict__ sc1, float* __restrict__ sb1,
        float* __restrict__ sc2, float* __restrict__ sb2)
{
    int i = blockIdx.x*256 + threadIdx.x;
    if (i < 262144) {
        w1bf[i] = f2b(f1w[i]);
        w2bf[i] = f2b(f2w[i]);
    }
    if (i < 49152) wbc[i] = f2b(bcdtw[i]);
    if (i < 1024) { float s = g1[i]*rsqrtf(v1[i]+NEPS); sc1[i]=s; sb1[i]=b1[i]-m1[i]*s; }
    if (i < 256)  { float s = g2[i]*rsqrtf(v2[i]+NEPS); sc2[i]=s; sb2[i]=b2[i]-m2[i]*s; }
}

// ---------- bc_dt = bcdt_w(192,256) @ LN(x1), MFMA; side-writes xn_bf ----------
// Block = (lb, 64-px tile), 4 waves; wave owns 48 output rows (3 m-frags).
__global__ __launch_bounds__(256) void bcdt_mfma(
        const float* __restrict__ x1,
        const float* __restrict__ meanp, const float* __restrict__ invp,
        const float* __restrict__ lnw, const float* __restrict__ lnb,
        const ushort* __restrict__ wbc,      // [192][256] bf16
        bf16* __restrict__ bc, ushort* __restrict__ xn_bf, int b0)
{
    __shared__ __align__(16) ushort Xs[64*256];  // [px][c] bf16, 16B-block XOR swizzle
    int blk = blockIdx.x;
    int lb = blk >> 6;
    int b  = b0 + lb;
    int l0 = (blk & 63) << 6;
    int tid = threadIdx.x, lane = tid & 63, w = tid >> 6;
    const float* xp = x1 + (size_t)b*256*4096 + l0;
    float mval = meanp[b*4096 + l0 + lane];
    float ival = invp [b*4096 + l0 + lane];
    ushort* xnp = xn_bf + (size_t)lb*256*4096 + l0;

    for (int cc = w*8; cc < 256; cc += 32) {
        ushort u[8];
        #pragma unroll
        for (int j=0;j<8;j++){
            float v = xp[(size_t)(cc+j)*4096 + lane];
            float xn = (v - mval)*ival*lnw[cc+j] + lnb[cc+j];
            u[j] = f2b(xn);
            xnp[(size_t)(cc+j)*4096 + lane] = u[j];
        }
        uint4 pk;
        pk.x = (uint)u[0] | ((uint)u[1]<<16);
        pk.y = (uint)u[2] | ((uint)u[3]<<16);
        pk.z = (uint)u[4] | ((uint)u[5]<<16);
        pk.w = (uint)u[6] | ((uint)u[7]<<16);
        int g = (cc>>3) ^ (lane&7);
        *(uint4*)&Xs[lane*256 + g*8] = pk;
    }
    __syncthreads();

    f32x4 zero4 = {0.f,0.f,0.f,0.f};
    f32x4 acc[3][4];
    #pragma unroll
    for (int m=0;m<3;m++)
        #pragma unroll
        for (int f=0;f<4;f++) acc[m][f] = zero4;

    int hbase = w*48;
    for (int ks=0; ks<8; ks++){
        bf16x8 afr[3];
        #pragma unroll
        for (int m=0;m<3;m++)
            afr[m] = *(const bf16x8*)&wbc[(size_t)(hbase + m*16 + (lane&15))*256
                                          + ks*32 + (lane>>4)*8];
        #pragma unroll
        for (int f=0;f<4;f++){
            int px = f*16 + (lane&15);
            int g = (ks*4 + (lane>>4)) ^ (px&7);
            bf16x8 bfr = *(const bf16x8*)&Xs[px*256 + g*8];
            #pragma unroll
            for (int m=0;m<3;m++)
                acc[m][f] = __builtin_amdgcn_mfma_f32_16x16x32_bf16(afr[m], bfr, acc[m][f], 0,0,0);
        }
    }
    bf16* op = bc + (size_t)lb*192*4096 + l0;
    #pragma unroll
    for (int m=0;m<3;m++)
        #pragma unroll
        for (int r=0;r<4;r++){
            int o = hbase + m*16 + (lane>>4)*4 + r;
            #pragma unroll
            for (int f=0;f<4;f++){
                int px = f*16 + (lane&15);
                op[(size_t)o*4096 + px] = __float2bfloat16(acc[m][f][r]);
            }
        }
}

// ---------- plain depthwise 3x3, in-place (192 channels per batch), bf16 ----------
__global__ __launch_bounds__(256) void dwconv_plain(bf16* __restrict__ data, const float* __restrict__ w)
{
    __shared__ float tile[66*66];
    int blk = blockIdx.x;
    int ch = blk % 192;
    bf16* xp = data + (size_t)blk*4096;
    int tid = threadIdx.x;
    for (int i = tid; i < 66*66; i += 256) {
        int r = i/66, c = i%66;
        int gr = r-1, gc = c-1;
        float val = 0.f;
        if (gr >= 0 && gr < 64 && gc >= 0 && gc < 64) val = LD(&xp[gr*64+gc]);
        tile[i] = val;
    }
    __syncthreads();
    float wv[9];
    #pragma unroll
    for (int k=0;k<9;k++) wv[k] = w[ch*9+k];
    for (int p = tid; p < 4096; p += 256) {
        int r = p>>6, c = p&63;
        float a = 0.f;
        #pragma unroll
        for (int dr=0;dr<3;dr++)
            #pragma unroll
            for (int dc=0;dc<3;dc++)
                a += wv[dr*3+dc]*tile[(r+dr)*66 + (c+dc)];
        ST(&xp[p], a);
    }
}

// ---------- softmax over L (per (lb,s)) and AB = Am*Bm in place over Bm rows ----------
__global__ __launch_bounds__(256) void softmax_ab(bf16* __restrict__ bc, const float* __restrict__ A)
{
    __shared__ float red[8];
    int blk = blockIdx.x;
    int lb = blk >> 6;
    int s = blk & 63;
    bf16* dtp = bc + ((size_t)lb*192 + 128 + s)*4096;
    bf16* bmp = bc + ((size_t)lb*192 + s)*4096;
    int tid = threadIdx.x;
    float Av = A[s];
    float vals[16];
    float mx = -1e30f;
    #pragma unroll
    for (int i=0;i<16;i++){ vals[i] = LD(&dtp[i*256+tid]) + Av; mx = fmaxf(mx, vals[i]); }
    #pragma unroll
    for (int o=32;o>0;o>>=1) mx = fmaxf(mx, __shfl_down(mx, o));
    int lane = tid & 63, wid = tid >> 6;
    if (lane == 0) red[wid] = mx;
    __syncthreads();
    if (tid == 0) red[4] = fmaxf(fmaxf(red[0],red[1]), fmaxf(red[2],red[3]));
    __syncthreads();
    mx = red[4];
    float sum = 0.f;
    #pragma unroll
    for (int i=0;i<16;i++){ vals[i] = expf(vals[i]-mx); sum += vals[i]; }
    #pragma unroll
    for (int o=32;o>0;o>>=1) sum += __shfl_down(sum, o);
    if (lane == 0) red[wid] = sum;
    __syncthreads();
    if (tid == 0) red[5] = red[0]+red[1]+red[2]+red[3];
    __syncthreads();
    float inv = 1.f/red[5];
    #pragma unroll
    for (int i=0;i<16;i++){
        float ab = vals[i]*inv*LD(&bmp[i*256+tid]);
        ST(&bmp[i*256+tid], ab);
    }
}

// ---------- h_part[lb][kz][c][s] = sum_{l in slice} xn[c,l]*AB[s,l], MFMA ----------
// Block = (lb, kz of 8 K-slices of 512); 4 waves; wave owns 64 c rows.
__global__ __launch_bounds__(256) void h_mfma(
        const ushort* __restrict__ xn_bf, const bf16* __restrict__ bc,
        float* __restrict__ h_part)
{
    int blk = blockIdx.x;
    int lb = blk >> 3;
    int kz = blk & 7;
    int kbase = kz*512;
    int tid = threadIdx.x, lane = tid & 63, w = tid >> 6;
    const ushort* ap = xn_bf + (size_t)lb*256*4096;
    const ushort* bp = (const ushort*)bc + (size_t)lb*192*4096;
    f32x4 zero4 = {0.f,0.f,0.f,0.f};
    f32x4 acc[4][4];
    #pragma unroll
    for (int m=0;m<4;m++)
        #pragma unroll
        for (int n=0;n<4;n++) acc[m][n] = zero4;

    for (int ks=0; ks<16; ks++){
        int koff = kbase + ks*32 + (lane>>4)*8;
        bf16x8 afr[4], bfr[4];
        #pragma unroll
        for (int m=0;m<4;m++)
            afr[m] = *(const bf16x8*)&ap[(size_t)(w*64 + m*16 + (lane&15))*4096 + koff];
        #pragma unroll
        for (int n=0;n<4;n++)
            bfr[n] = *(const bf16x8*)&bp[(size_t)(n*16 + (lane&15))*4096 + koff];
        #pragma unroll
        for (int m=0;m<4;m++)
            #pragma unroll
            for (int n=0;n<4;n++)
                acc[m][n] = __builtin_amdgcn_mfma_f32_16x16x32_bf16(afr[m], bfr[n], acc[m][n], 0,0,0);
    }
    float* hp = h_part + ((size_t)lb*8 + kz)*16384;
    #pragma unroll
    for (int m=0;m<4;m++)
        #pragma unroll
        for (int n=0;n<4;n++)
            #pragma unroll
            for (int r=0;r<4;r++){
                int c = w*64 + m*16 + (lane>>4)*4 + r;
                int s = n*16 + (lane&15);
                hp[c*64 + s] = acc[m][n][r];
            }
}

// ---------- hz = hz_w(512,256) @ h  (sums 8 h_part slices during staging) ----------
__global__ __launch_bounds__(256) void hz_gemm(const float* __restrict__ h_part,
        const float* __restrict__ w, float* __restrict__ hz)
{
    __shared__ float ht[256][64];
    int blk = blockIdx.x; int lb = blk>>3; int o0 = (blk&7)*64;
    int tid = threadIdx.x;
    const float* hp = h_part + (size_t)lb*8*16384;
    for (int i=tid;i<16384;i+=256){
        float s = 0.f;
        #pragma unroll
        for (int k=0;k<8;k++) s += hp[k*16384 + i];
        ht[i>>6][i&63] = s;
    }
    __syncthreads();
    int lane=tid&63, g=tid>>6;
    for (int i4=0;i4<4;i4++){
        int ol = g*16 + i4*4;
        const float* r0 = w + (size_t)(o0+ol)*256;
        const float *r1=r0+256, *r2=r0+512, *r3=r0+768;
        float d0=0.f,d1=0.f,d2=0.f,d3=0.f;
        #pragma unroll 8
        for (int c4=0;c4<64;c4++){
            float x0=ht[c4*4][lane],x1v=ht[c4*4+1][lane],x2v=ht[c4*4+2][lane],x3v=ht[c4*4+3][lane];
            float4 a0=((const float4*)r0)[c4],a1=((const float4*)r1)[c4];
            float4 a2=((const float4*)r2)[c4],a3=((const float4*)r3)[c4];
            d0 += a0.x*x0+a0.y*x1v+a0.z*x2v+a0.w*x3v;
            d1 += a1.x*x0+a1.y*x1v+a1.z*x2v+a1.w*x3v;
            d2 += a2.x*x0+a2.y*x1v+a2.z*x2v+a2.w*x3v;
            d3 += a3.x*x0+a3.y*x1v+a3.z*x2v+a3.w*x3v;
        }
        size_t base = ((size_t)lb*512 + o0 + ol)*64 + lane;
        hz[base]=d0; hz[base+64]=d1; hz[base+128]=d2; hz[base+192]=d3;
    }
}

// ---------- hg = hh*(silu(z)+D) ----------
__global__ void gate_k(const float* __restrict__ hz, float* __restrict__ hg, const float* __restrict__ Dp)
{
    int i = blockIdx.x*256 + threadIdx.x;
    int lb = i >> 14;
    int r = i & 16383;
    const float* hp = hz + (size_t)lb*32768;
    float hh = hp[r], z = hp[16384 + r];
    float sil = z / (1.f + expf(-z));
    hg[i] = hh * (sil + Dp[0]);
}

// ---------- hout = out_w(256,256) @ hg ; writes bf16 ws copy + f32 d_out copy ----------
__global__ __launch_bounds__(256) void out_gemm(const float* __restrict__ hg, const float* __restrict__ w,
        ushort* __restrict__ hout_bf, float* __restrict__ hout_out, int b0)
{
    __shared__ float ht[256][64];
    int blk = blockIdx.x; int lb = blk>>2; int b = b0 + lb; int o0 = (blk&3)*64;
    int tid = threadIdx.x;
    const float* hp = hg + (size_t)lb*16384;
    for (int i=tid;i<16384;i+=256) ht[i>>6][i&63]=hp[i];
    __syncthreads();
    int lane=tid&63, g=tid>>6;
    for (int i4=0;i4<4;i4++){
        int ol = g*16 + i4*4;
        const float* r0 = w + (size_t)(o0+ol)*256;
        const float *r1=r0+256, *r2=r0+512, *r3=r0+768;
        float d0=0.f,d1=0.f,d2=0.f,d3=0.f;
        #pragma unroll 8
        for (int c4=0;c4<64;c4++){
            float x0=ht[c4*4][lane],x1v=ht[c4*4+1][lane],x2v=ht[c4*4+2][lane],x3v=ht[c4*4+3][lane];
            float4 a0=((const float4*)r0)[c4],a1=((const float4*)r1)[c4];
            float4 a2=((const float4*)r2)[c4],a3=((const float4*)r3)[c4];
            d0 += a0.x*x0+a0.y*x1v+a0.z*x2v+a0.w*x3v;
            d1 += a1.x*x0+a1.y*x1v+a1.z*x2v+a1.w*x3v;
            d2 += a2.x*x0+a2.y*x1v+a2.z*x2v+a2.w*x3v;
            d3 += a3.x*x0+a3.y*x1v+a3.z*x2v+a3.w*x3v;
        }
        size_t lbase = ((size_t)lb*256 + o0 + ol)*64 + lane;
        hout_bf[lbase]=f2b(d0); hout_bf[lbase+64]=f2b(d1);
        hout_bf[lbase+128]=f2b(d2); hout_bf[lbase+192]=f2b(d3);
        size_t gbase = ((size_t)b*256 + o0 + ol)*64 + lane;
        hout_out[gbase]=d0; hout_out[gbase+64]=d1;
        hout_out[gbase+128]=d2; hout_out[gbase+192]=d3;
    }
}

// ---------- y = hout @ Cm (MFMA) ; x2 = (1-a1)*x1 + a1*y in place on x1 ----------
// Block = (lb, 64-px tile), 4 waves; wave owns 64 c rows; K = 64 s.
__global__ __launch_bounds__(256) void y_mfma(
        const ushort* __restrict__ hout_bf, const bf16* __restrict__ bc,
        float* __restrict__ x1, const float* __restrict__ alpha, int b0)
{
    __shared__ __align__(16) ushort Cs[64*64];   // [px][s] bf16, swizzled
    int blk = blockIdx.x; int lb = blk>>6; int b = b0 + lb; int l0 = (blk&63)<<6;
    int tid = threadIdx.x, lane = tid&63, w = tid>>6;
    const ushort* cp = (const ushort*)bc + ((size_t)lb*192 + 64)*4096 + l0;
    for (int sc = w*8; sc < 64; sc += 32){
        ushort u[8];
        #pragma unroll
        for (int j=0;j<8;j++) u[j] = cp[(size_t)(sc+j)*4096 + lane];
        uint4 pk;
        pk.x = (uint)u[0] | ((uint)u[1]<<16);
        pk.y = (uint)u[2] | ((uint)u[3]<<16);
        pk.z = (uint)u[4] | ((uint)u[5]<<16);
        pk.w = (uint)u[6] | ((uint)u[7]<<16);
        int g = (sc>>3) ^ (lane&7);
        *(uint4*)&Cs[lane*64 + g*8] = pk;
    }
    __syncthreads();

    f32x4 zero4 = {0.f,0.f,0.f,0.f};
    f32x4 acc[4][4];
    #pragma unroll
    for (int m=0;m<4;m++)
        #pragma unroll
        for (int f=0;f<4;f++) acc[m][f] = zero4;

    const ushort* ap = hout_bf + (size_t)lb*256*64;
    #pragma unroll
    for (int ks=0; ks<2; ks++){
        bf16x8 afr[4];
        #pragma unroll
        for (int m=0;m<4;m++)
            afr[m] = *(const bf16x8*)&ap[(size_t)(w*64 + m*16 + (lane&15))*64
                                          + ks*32 + (lane>>4)*8];
        #pragma unroll
        for (int f=0;f<4;f++){
            int px = f*16 + (lane&15);
            int s8 = ks*32 + (lane>>4)*8;
            int g = (s8>>3) ^ (px&7);
            bf16x8 bfr = *(const bf16x8*)&Cs[px*64 + g*8];
            #pragma unroll
            for (int m=0;m<4;m++)
                acc[m][f] = __builtin_amdgcn_mfma_f32_16x16x32_bf16(afr[m], bfr, acc[m][f], 0,0,0);
        }
    }

    float* xpo = x1 + (size_t)b*256*4096 + l0;
    #pragma unroll
    for (int m=0;m<4;m++)
        #pragma unroll
        for (int r=0;r<4;r++){
            int c = w*64 + m*16 + (lane>>4)*4 + r;
            float av = sigm(alpha[256+c]);
            #pragma unroll
            for (int f=0;f<4;f++){
                int px = f*16 + (lane&15);
                float xv = xpo[(size_t)c*4096 + px];
                xpo[(size_t)c*4096 + px] = (1.f-av)*xv + av*acc[m][f][r];
            }
        }
}

// ---------- MFMA FFN: relu(bn1(fc1@x)) -> bn2(fc2@t) -> alpha blend, in place ----------
__global__ __launch_bounds__(256) void ffn_mfma(
        const float* __restrict__ x,
        const ushort* __restrict__ w1bf,  // [1024][256]
        const ushort* __restrict__ w2bf,  // [256][1024]
        const float* __restrict__ sc1, const float* __restrict__ sb1,
        const float* __restrict__ sc2, const float* __restrict__ sb2,
        const float* __restrict__ alpha,
        float* __restrict__ out)
{
    __shared__ __align__(16) ushort Xs[64*256];  // [px][c] bf16, 16B-block XOR swizzle
    __shared__ __align__(16) ushort Ts[64*128];  // [px][h_local] bf16, swizzled
    int blk = blockIdx.x;
    int b = blk >> 6, l0 = (blk & 63) << 6;
    int tid = threadIdx.x, lane = tid & 63, w = tid >> 6;
    const float* xp = x + (size_t)b*256*4096 + l0;

    for (int cc = w*8; cc < 256; cc += 32) {
        float v[8];
        #pragma unroll
        for (int j=0;j<8;j++) v[j] = xp[(size_t)(cc+j)*4096 + lane];
        uint4 pk;
        pk.x = (uint)f2b(v[0]) | ((uint)f2b(v[1])<<16);
        pk.y = (uint)f2b(v[2]) | ((uint)f2b(v[3])<<16);
        pk.z = (uint)f2b(v[4]) | ((uint)f2b(v[5])<<16);
        pk.w = (uint)f2b(v[6]) | ((uint)f2b(v[7])<<16);
        int g = (cc>>3) ^ (lane&7);
        *(uint4*)&Xs[lane*256 + g*8] = pk;
    }
    __syncthreads();

    f32x4 zero4 = {0.f,0.f,0.f,0.f};
    f32x4 acc2[4][4];
    #pragma unroll
    for (int m=0;m<4;m++)
        #pragma unroll
        for (int f=0;f<4;f++) acc2[m][f] = zero4;

    for (int hc = 0; hc < 1024; hc += 128) {
        int hbase = hc + w*32;
        f32x4 c1[2][4];
        #pragma unroll
        for (int m=0;m<2;m++)
            #pragma unroll
            for (int f=0;f<4;f++) c1[m][f] = zero4;
        for (int ks = 0; ks < 8; ks++) {
            bf16x8 afr[2];
            #pragma unroll
            for (int m=0;m<2;m++)
                afr[m] = *(const bf16x8*)&w1bf[(size_t)(hbase + m*16 + (lane&15))*256
                                               + ks*32 + (lane>>4)*8];
            #pragma unroll
            for (int f=0;f<4;f++){
                int px = f*16 + (lane&15);
                int g = (ks*4 + (lane>>4)) ^ (px&7);
                bf16x8 bfr = *(const bf16x8*)&Xs[px*256 + g*8];
                #pragma unroll
                for (int m=0;m<2;m++)
                    c1[m][f] = __builtin_amdgcn_mfma_f32_16x16x32_bf16(afr[m], bfr, c1[m][f], 0,0,0);
            }
        }
        __syncthreads();
        #pragma unroll
        for (int m=0;m<2;m++){
            #pragma unroll
            for (int r=0;r<4;r++){
                int h = hbase + m*16 + (lane>>4)*4 + r;
                float s1 = sc1[h], bb1 = sb1[h];
                int hl = h - hc;
                #pragma unroll
                for (int f=0;f<4;f++){
                    int px = f*16 + (lane&15);
                    float t = fmaxf(c1[m][f][r]*s1 + bb1, 0.f);
                    int g = (hl>>3) ^ (px&7);
                    Ts[px*128 + g*8 + (hl&7)] = f2b(t);
                }
            }
        }
        __syncthreads();
        int c0 = w*64;
        for (int ks = 0; ks < 4; ks++) {
            bf16x8 afr[4];
            #pragma unroll
            for (int m=0;m<4;m++)
                afr[m] = *(const bf16x8*)&w2bf[(size_t)(c0 + m*16 + (lane&15))*1024
                                               + hc + ks*32 + (lane>>4)*8];
            #pragma unroll
            for (int f=0;f<4;f++){
                int px = f*16 + (lane&15);
                int hl = ks*32 + (lane>>4)*8;
                int g = (hl>>3) ^ (px&7);
                bf16x8 bfr = *(const bf16x8*)&Ts[px*128 + g*8];
                #pragma unroll
                for (int m=0;m<4;m++)
                    acc2[m][f] = __builtin_amdgcn_mfma_f32_16x16x32_bf16(afr[m], bfr, acc2[m][f], 0,0,0);
            }
        }
    }

    float* op = out + (size_t)b*256*4096 + l0;
    int c0 = w*64;
    #pragma unroll
    for (int m=0;m<4;m++){
        #pragma unroll
        for (int r=0;r<4;r++){
            int c = c0 + m*16 + (lane>>4)*4 + r;
            float a = sigm(alpha[768+c]);
            float s2 = sc2[c], bb2 = sb2[c];
            #pragma unroll
            for (int f=0;f<4;f++){
                int px = f*16 + (lane&15);
                float t2 = acc2[m][f][r]*s2 + bb2;
                float xv = xp[(size_t)c*4096 + px];
                op[(size_t)c*4096 + px] = (1.f-a)*xv + a*t2;
            }
        }
    }
}

extern "C" void kernel_launch(void* const* d_in, const int* in_sizes, int n_in,
                              void* d_out, int out_size, void* d_ws, size_t ws_size,
                              hipStream_t stream)
{
    (void)in_sizes; (void)n_in; (void)out_size;
    const float* x     = (const float*)d_in[0];
    const float* dw1w  = (const float*)d_in[1];
    const float* dw1g  = (const float*)d_in[2];
    const float* dw1b  = (const float*)d_in[3];
    const float* dw1m  = (const float*)d_in[4];
    const float* dw1v  = (const float*)d_in[5];
    const float* lnw   = (const float*)d_in[6];
    const float* lnb   = (const float*)d_in[7];
    const float* bcdtw = (const float*)d_in[8];
    const float* dwmw  = (const float*)d_in[9];
    const float* Ap    = (const float*)d_in[10];
    const float* hzw   = (const float*)d_in[11];
    const float* outw  = (const float*)d_in[12];
    const float* Dp    = (const float*)d_in[13];
    const float* dw2w  = (const float*)d_in[14];
    const float* dw2g  = (const float*)d_in[15];
    const float* dw2b  = (const float*)d_in[16];
    const float* dw2m  = (const float*)d_in[17];
    const float* dw2v  = (const float*)d_in[18];
    const float* f1w   = (const float*)d_in[19];
    const float* f1g   = (const float*)d_in[20];
    const float* f1b   = (const float*)d_in[21];
    const float* f1m   = (const float*)d_in[22];
    const float* f1v   = (const float*)d_in[23];
    const float* f2w   = (const float*)d_in[24];
    const float* f2g   = (const float*)d_in[25];
    const float* f2b_  = (const float*)d_in[26];
    const float* f2m   = (const float*)d_in[27];
    const float* f2v   = (const float*)d_in[28];
    const float* alpha = (const float*)d_in[29];

    const size_t nx = (size_t)32*256*4096;
    float* x1 = (float*)d_out;          // x1 lives in d_out's x region
    float* hout_out = x1 + nx;          // hout output region (f32)

    char* ws = (char*)d_ws;
    float* meanp = (float*)ws;                       // 512 KB
    float* invp  = meanp + 131072;                   // 512 KB
    size_t off = 1048576;
    ushort* w1bf = (ushort*)(ws + off); off += 524288;
    ushort* w2bf = (ushort*)(ws + off); off += 524288;
    ushort* wbc  = (ushort*)(ws + off); off += 98304;
    float* sc1 = (float*)(ws + off); off += 4096;
    float* sb1 = (float*)(ws + off); off += 4096;
    float* sc2 = (float*)(ws + off); off += 1024;
    float* sb2 = (float*)(ws + off); off += 1024;
    off = (off + 255) & ~(size_t)255;
    char* cbase = ws + off;
    size_t avail = ws_size > off ? ws_size - off : 0;

    // per-b: bc 1.5M + xn_bf 2M + h_part 512K + hz 128K + hg 64K + hout_bf 32K
    const size_t perb = 1572864 + 2097152 + 524288 + 131072 + 65536 + 32768; // 4,423,680
    int NB = 1;
    for (int nb = 32; nb >= 1; nb >>= 1) if (avail >= (size_t)nb*perb) { NB = nb; break; }

    prep_k<<<1024,256,0,stream>>>(f1w, f2w, bcdtw, f1g,f1b,f1m,f1v, f2g,f2b_,f2m,f2v,
                                  w1bf, w2bf, wbc, sc1, sb1, sc2, sb2);
    dwconv_bn_blend<<<8192,256,0,stream>>>(x, x1, dw1w,dw1g,dw1b,dw1m,dw1v, alpha, 0);
    ln_stats<<<512,256,0,stream>>>(x1, meanp, invp);

    bf16*   bc      = (bf16*)cbase;
    ushort* xn_bf   = (ushort*)(cbase + (size_t)NB*1572864);
    float*  h_part  = (float*)(cbase + (size_t)NB*(1572864 + 2097152));
    float*  hz      = (float*)((char*)h_part + (size_t)NB*524288);
    float*  hg      = (float*)((char*)hz + (size_t)NB*131072);
    ushort* hout_bf = (ushort*)((char*)hg + (size_t)NB*65536);

    for (int b0 = 0; b0 < 32; b0 += NB) {
        bcdt_mfma<<<NB*64,256,0,stream>>>(x1, meanp, invp, lnw, lnb, wbc, bc, xn_bf, b0);
        dwconv_plain<<<NB*192,256,0,stream>>>(bc, dwmw);
        softmax_ab<<<NB*64,256,0,stream>>>(bc, Ap);
        h_mfma<<<NB*8,256,0,stream>>>(xn_bf, bc, h_part);
        hz_gemm<<<NB*8,256,0,stream>>>(h_part, hzw, hz);
        gate_k<<<NB*64,256,0,stream>>>(hz, hg, Dp);
        out_gemm<<<NB*4,256,0,stream>>>(hg, outw, hout_bf, hout_out, b0);
        y_mfma<<<NB*64,256,0,stream>>>(hout_bf, bc, x1, alpha, b0);
    }

    dwconv_bn_blend<<<8192,256,0,stream>>>(x1, x1, dw2w,dw2g,dw2b,dw2m,dw2v, alpha, 2);
    ffn_mfma<<<2048,256,0,stream>>>(x1, w1bf, w2bf, sc1, sb1, sc2, sb2, alpha, x1);
}